// Round 1
// baseline (243.699 us; speedup 1.0000x reference)
//
#include <hip/hip_runtime.h>
#include <hip/hip_bf16.h>

#define HID   128
#define PITCH 136   // only used by the fp32 fallback's LDS tile
#define TPB   256

typedef __attribute__((ext_vector_type(8))) __bf16 bf16x8;
typedef __attribute__((ext_vector_type(4))) __bf16 bf16x4;
typedef __attribute__((ext_vector_type(4))) float  f32x4;

// --- prep: grid-stride cast x fp32 -> xb bf16 (coalesced).
//     First 2048 global threads also transpose W1 -> w1t[n*HID+k] via direct
//     global reads (64 KB, L2-hot) — NO LDS, so the cast runs at full occupancy.
__global__ __launch_bounds__(TPB) void prep_kernel(
    const float* __restrict__ W1, __bf16* __restrict__ w1t,
    const float* __restrict__ x, __bf16* __restrict__ xb, int n_x4) {
  if (xb) {
    for (int i = blockIdx.x * TPB + threadIdx.x; i < n_x4; i += gridDim.x * TPB) {
      float4 a = reinterpret_cast<const float4*>(x)[i];
      bf16x4 v;
      v[0] = (__bf16)a.x; v[1] = (__bf16)a.y; v[2] = (__bf16)a.z; v[3] = (__bf16)a.w;
      reinterpret_cast<bf16x4*>(xb)[i] = v;
    }
  }
  if (w1t) {
    const int gid = blockIdx.x * TPB + threadIdx.x;
    if (gid < HID * (HID / 8)) {
      const int n  = gid >> 4;
      const int k0 = (gid & 15) << 3;
      bf16x8 v;
#pragma unroll
      for (int j = 0; j < 8; ++j) v[j] = (__bf16)W1[(k0 + j) * HID + n];
      *reinterpret_cast<bf16x8*>(&w1t[n * HID + k0]) = v;
    }
  }
}

// 16x16x32 MFMA decode, LDS-free:
//  - all 32 W1 B-fragments hoisted to registers (loop-invariant)
//  - b1/W2 hoisted to registers; acc initialized with b1 (C cols = lane m)
//  - row gathers software-pipelined one tile ahead, reusing S/D regs per-kt
__global__ __launch_bounds__(TPB, 2) void vgae_decode_kernel(
    const __bf16* __restrict__ xb,
    const __bf16* __restrict__ w1t,
    const float* __restrict__ b1,
    const float* __restrict__ W2,
    const float* __restrict__ b2,
    const int* __restrict__ eip,
    const int* __restrict__ ein,
    float* __restrict__ out,
    int E, int n_tiles)
{
  const int lane = threadIdx.x & 63;
  const int wave = threadIdx.x >> 6;
  const int m    = lane & 15;   // edge-within-wave (A row) / n-col (B col, C col)
  const int quad = lane >> 4;   // k-chunk for A/B frags; C row group
  const float b2v = b2[0];

  // hoist B: 32 x bf16x8 = 128 VGPR, read once per wave (L2-hot after warmup)
  bf16x8 Bf[8][4];
#pragma unroll
  for (int nt = 0; nt < 8; ++nt)
#pragma unroll
    for (int kt = 0; kt < 4; ++kt)
      Bf[nt][kt] = *reinterpret_cast<const bf16x8*>(
          w1t + (nt * 16 + m) * HID + kt * 32 + quad * 8);

  float b1v[8], w2v[8];
#pragma unroll
  for (int nt = 0; nt < 8; ++nt) {
    b1v[nt] = b1[nt * 16 + m];
    w2v[nt] = W2[nt * 16 + m];
  }

  int tile = blockIdx.x;
  if (tile >= n_tiles) return;

  bf16x8 S[4], D[4];
  int nsrc = 0, ndst = 0;

  // prologue: idx(t0) -> rows(t0); then issue idx(t1)
  {
    const int e_base = tile * 64 + wave * 16;
    const int* ei = (e_base < E) ? eip : ein;
    const int  eo = (e_base < E) ? e_base : (e_base - E);
    const int s0 = ei[eo + m];
    const int d0 = ei[E + eo + m];
    const __bf16* xs = xb + (size_t)s0 * HID;
    const __bf16* xd = xb + (size_t)d0 * HID;
#pragma unroll
    for (int kt = 0; kt < 4; ++kt) {
      const int k0 = kt * 32 + quad * 8;
      S[kt] = *reinterpret_cast<const bf16x8*>(xs + k0);
      D[kt] = *reinterpret_cast<const bf16x8*>(xd + k0);
    }
  }
  {
    const int tn = tile + gridDim.x;
    if (tn < n_tiles) {
      const int e_base = tn * 64 + wave * 16;
      const int* ei = (e_base < E) ? eip : ein;
      const int  eo = (e_base < E) ? e_base : (e_base - E);
      nsrc = ei[eo + m];
      ndst = ei[E + eo + m];
    }
  }

  for (; tile < n_tiles; tile += gridDim.x) {
    const int tn = tile + gridDim.x;
    // next tile's row base pointers (valid even when stale; loads then guarded)
    const __bf16* nxs = xb + (size_t)nsrc * HID;
    const __bf16* nxd = xb + (size_t)ndst * HID;

    // issue idx load for tile t+2 (arrives by top of next iteration)
    const int tnn = tn + gridDim.x;
    if (tnn < n_tiles) {
      const int e_base = tnn * 64 + wave * 16;
      const int* ei = (e_base < E) ? eip : ein;
      const int  eo = (e_base < E) ? e_base : (e_base - E);
      nsrc = ei[eo + m];
      ndst = ei[E + eo + m];
    }

    // acc init = b1 broadcast (C layout: col n = m, shared by all 4 rows)
    f32x4 acc[8];
#pragma unroll
    for (int nt = 0; nt < 8; ++nt) {
      f32x4 t;
      t[0] = b1v[nt]; t[1] = b1v[nt]; t[2] = b1v[nt]; t[3] = b1v[nt];
      acc[nt] = t;
    }

#pragma unroll
    for (int kt = 0; kt < 4; ++kt) {
      const int k0 = kt * 32 + quad * 8;
      bf16x8 a;   // h = relu(x_s * x_d), A-frag layout
#pragma unroll
      for (int j = 0; j < 8; ++j) {
        float pr = (float)S[kt][j] * (float)D[kt][j];
        a[j] = (__bf16)fmaxf(pr, 0.f);
      }
      // S[kt]/D[kt] consumed -> immediately refill with next tile's rows;
      // latency hidden under remaining MFMA + epilogue (~600+ cyc)
      if (tn < n_tiles) {
        S[kt] = *reinterpret_cast<const bf16x8*>(nxs + k0);
        D[kt] = *reinterpret_cast<const bf16x8*>(nxd + k0);
      }
#pragma unroll
      for (int nt = 0; nt < 8; ++nt)
        acc[nt] = __builtin_amdgcn_mfma_f32_16x16x32_bf16(a, Bf[nt][kt], acc[nt], 0, 0, 0);
    }

    // epilogue: p[r] = sum_n relu(C[row][n]) * W2[n]   (bias already in acc)
    float p[4] = {0.f, 0.f, 0.f, 0.f};
#pragma unroll
    for (int nt = 0; nt < 8; ++nt) {
#pragma unroll
      for (int r = 0; r < 4; ++r)
        p[r] = fmaf(fmaxf(acc[nt][r], 0.f), w2v[nt], p[r]);
    }
#pragma unroll
    for (int off = 1; off < 16; off <<= 1) {
#pragma unroll
      for (int r = 0; r < 4; ++r) p[r] += __shfl_xor(p[r], off, 64);
    }
    if (m == 0) {
      float4 o;
      o.x = 1.f / (1.f + __expf(-(p[0] + b2v)));
      o.y = 1.f / (1.f + __expf(-(p[1] + b2v)));
      o.z = 1.f / (1.f + __expf(-(p[2] + b2v)));
      o.w = 1.f / (1.f + __expf(-(p[3] + b2v)));
      *reinterpret_cast<float4*>(out + tile * 64 + wave * 16 + quad * 4) = o;
    }
  }
}

// fp32 fallback (ws too small for xb): unchanged structure
__global__ __launch_bounds__(TPB) void vgae_decode_fallback(
    const float* __restrict__ x,
    const float* __restrict__ W1,
    const float* __restrict__ b1,
    const float* __restrict__ W2,
    const float* __restrict__ b2,
    const int* __restrict__ eip,
    const int* __restrict__ ein,
    float* __restrict__ out,
    int E, int n_tiles)
{
  __shared__ __bf16 sW[HID * PITCH];
  __shared__ float  sb1[HID];
  __shared__ float  sw2[HID];
  for (int c = threadIdx.x; c < HID * (HID / 8); c += TPB) {
    int n = c >> 4, k0 = (c & 15) << 3;
    bf16x8 v;
#pragma unroll
    for (int j = 0; j < 8; ++j) v[j] = (__bf16)W1[(k0 + j) * HID + n];
    *reinterpret_cast<bf16x8*>(&sW[n * PITCH + k0]) = v;
  }
  if (threadIdx.x < HID) { sb1[threadIdx.x] = b1[threadIdx.x]; sw2[threadIdx.x] = W2[threadIdx.x]; }
  __syncthreads();
  const int lane = threadIdx.x & 63, wave = threadIdx.x >> 6;
  const int m = lane & 15, quad = lane >> 4;
  const float b2v = b2[0];
  for (int tile = blockIdx.x; tile < n_tiles; tile += gridDim.x) {
    const int e_base = tile * 64 + wave * 16;
    const int* ei = (e_base < E) ? eip : ein;
    const int  eo = (e_base < E) ? e_base : (e_base - E);
    const int src = ei[eo + m], dst = ei[E + eo + m];
    const float* xs = x + (size_t)src * HID;
    const float* xd = x + (size_t)dst * HID;
    f32x4 acc[8] = {};
#pragma unroll
    for (int kt = 0; kt < 4; ++kt) {
      const int k0 = kt * 32 + quad * 8;
      float4 s0 = *reinterpret_cast<const float4*>(xs + k0);
      float4 s1 = *reinterpret_cast<const float4*>(xs + k0 + 4);
      float4 d0 = *reinterpret_cast<const float4*>(xd + k0);
      float4 d1 = *reinterpret_cast<const float4*>(xd + k0 + 4);
      bf16x8 a;
      a[0] = (__bf16)fmaxf(s0.x * d0.x, 0.f); a[1] = (__bf16)fmaxf(s0.y * d0.y, 0.f);
      a[2] = (__bf16)fmaxf(s0.z * d0.z, 0.f); a[3] = (__bf16)fmaxf(s0.w * d0.w, 0.f);
      a[4] = (__bf16)fmaxf(s1.x * d1.x, 0.f); a[5] = (__bf16)fmaxf(s1.y * d1.y, 0.f);
      a[6] = (__bf16)fmaxf(s1.z * d1.z, 0.f); a[7] = (__bf16)fmaxf(s1.w * d1.w, 0.f);
#pragma unroll
      for (int nt = 0; nt < 8; ++nt) {
        bf16x8 bfr = *reinterpret_cast<const bf16x8*>(&sW[(nt * 16 + m) * PITCH + k0]);
        acc[nt] = __builtin_amdgcn_mfma_f32_16x16x32_bf16(a, bfr, acc[nt], 0, 0, 0);
      }
    }
    float p[4] = {0.f, 0.f, 0.f, 0.f};
#pragma unroll
    for (int nt = 0; nt < 8; ++nt) {
      const int n = nt * 16 + m;
      const float b1n = sb1[n], w2n = sw2[n];
#pragma unroll
      for (int r = 0; r < 4; ++r) p[r] = fmaf(fmaxf(acc[nt][r] + b1n, 0.f), w2n, p[r]);
    }
#pragma unroll
    for (int off = 1; off < 16; off <<= 1)
#pragma unroll
      for (int r = 0; r < 4; ++r) p[r] += __shfl_xor(p[r], off, 64);
    if (m == 0) {
      float4 o;
      o.x = 1.f / (1.f + __expf(-(p[0] + b2v)));
      o.y = 1.f / (1.f + __expf(-(p[1] + b2v)));
      o.z = 1.f / (1.f + __expf(-(p[2] + b2v)));
      o.w = 1.f / (1.f + __expf(-(p[3] + b2v)));
      *reinterpret_cast<float4*>(out + tile * 64 + wave * 16 + quad * 4) = o;
    }
  }
}

extern "C" void kernel_launch(void* const* d_in, const int* in_sizes, int n_in,
                              void* d_out, int out_size, void* d_ws, size_t ws_size,
                              hipStream_t stream) {
  const float* x  = (const float*)d_in[0];
  const float* W1 = (const float*)d_in[1];
  const float* b1 = (const float*)d_in[2];
  const float* W2 = (const float*)d_in[3];
  const float* b2 = (const float*)d_in[4];
  const int*  eip = (const int*)d_in[5];
  const int*  ein = (const int*)d_in[6];
  float* out = (float*)d_out;
  const int E = in_sizes[5] / 2;
  const int n_tiles = (2 * E) / 64;
  const int n_nodes = in_sizes[0] / HID;
  const int n_x4 = in_sizes[0] / 4;

  const size_t w1t_bytes = (size_t)HID * HID * sizeof(__bf16);
  const size_t xb_off    = 65536;
  const size_t xb_bytes  = (size_t)n_nodes * HID * sizeof(__bf16);

  __bf16* w1t = nullptr;
  __bf16* xb  = nullptr;
  if (ws_size >= w1t_bytes) w1t = (__bf16*)d_ws;
  if (ws_size >= xb_off + xb_bytes) xb = (__bf16*)((char*)d_ws + xb_off);

  if (w1t && xb) {
    int prep_grid = (n_x4 + TPB - 1) / TPB;
    if (prep_grid > 6400) prep_grid = 6400;
    prep_kernel<<<prep_grid, TPB, 0, stream>>>(W1, w1t, x, xb, n_x4);
    vgae_decode_kernel<<<1024, TPB, 0, stream>>>(xb, w1t, b1, W2, b2,
                                                 eip, ein, out, E, n_tiles);
  } else {
    vgae_decode_fallback<<<2560, TPB, 0, stream>>>(x, W1, b1, W2, b2,
                                                   eip, ein, out, E, n_tiles);
  }
}

// Round 2
// 199.342 us; speedup vs baseline: 1.2225x; 1.2225x over previous
//
#include <hip/hip_runtime.h>
#include <hip/hip_bf16.h>

#define HID   128
#define PITCH 136   // only used by the fp32 fallback's LDS tile
#define TPB   256

typedef __attribute__((ext_vector_type(8))) __bf16 bf16x8;
typedef __attribute__((ext_vector_type(4))) __bf16 bf16x4;
typedef __attribute__((ext_vector_type(4))) float  f32x4;

// --- prep: grid-stride cast x fp32 -> xb bf16 (coalesced).
//     First 2048 global threads also transpose W1 -> w1t[n*HID+k] via direct
//     global reads (64 KB, L2-hot) — NO LDS, so the cast runs at full occupancy.
__global__ __launch_bounds__(TPB) void prep_kernel(
    const float* __restrict__ W1, __bf16* __restrict__ w1t,
    const float* __restrict__ x, __bf16* __restrict__ xb, int n_x4) {
  if (xb) {
    for (int i = blockIdx.x * TPB + threadIdx.x; i < n_x4; i += gridDim.x * TPB) {
      float4 a = reinterpret_cast<const float4*>(x)[i];
      bf16x4 v;
      v[0] = (__bf16)a.x; v[1] = (__bf16)a.y; v[2] = (__bf16)a.z; v[3] = (__bf16)a.w;
      reinterpret_cast<bf16x4*>(xb)[i] = v;
    }
  }
  if (w1t) {
    const int gid = blockIdx.x * TPB + threadIdx.x;
    if (gid < HID * (HID / 8)) {
      const int n  = gid >> 4;
      const int k0 = (gid & 15) << 3;
      bf16x8 v;
#pragma unroll
      for (int j = 0; j < 8; ++j) v[j] = (__bf16)W1[(k0 + j) * HID + n];
      *reinterpret_cast<bf16x8*>(&w1t[n * HID + k0]) = v;
    }
  }
}

// 16x16x32 MFMA decode, LDS-free, register-resident W1:
//  - all 32 W1 B-fragments hoisted to registers (128 VGPR, loop-invariant)
//  - launch_bounds(256,1): 512-reg budget -> no spill; real occupancy ~2 w/EU
//  - uniform control flow: prefetch indices CLAMPED to last tile (no guards)
//  - b1 pre-loaded into the MFMA accumulator; b1/W2 in registers
//  - row gathers software-pipelined one tile ahead via per-kt S/D refill
__global__ __launch_bounds__(TPB, 1) void vgae_decode_kernel(
    const __bf16* __restrict__ xb,
    const __bf16* __restrict__ w1t,
    const float* __restrict__ b1,
    const float* __restrict__ W2,
    const float* __restrict__ b2,
    const int* __restrict__ eip,
    const int* __restrict__ ein,
    float* __restrict__ out,
    int E, int n_tiles)
{
  const int lane = threadIdx.x & 63;
  const int wave = threadIdx.x >> 6;
  const int m    = lane & 15;   // edge-within-wave (A row) / n-col (B col, C col)
  const int quad = lane >> 4;   // k-chunk for A/B frags; C row group
  const float b2v = b2[0];

  // hoist B: 32 x bf16x8 = 128 VGPR, read once per wave (L2-hot)
  bf16x8 Bf[8][4];
#pragma unroll
  for (int nt = 0; nt < 8; ++nt)
#pragma unroll
    for (int kt = 0; kt < 4; ++kt)
      Bf[nt][kt] = *reinterpret_cast<const bf16x8*>(
          w1t + (nt * 16 + m) * HID + kt * 32 + quad * 8);

  float b1v[8], w2v[8];
#pragma unroll
  for (int nt = 0; nt < 8; ++nt) {
    b1v[nt] = b1[nt * 16 + m];
    w2v[nt] = W2[nt * 16 + m];
  }

  const int stride = gridDim.x;
  const int last   = n_tiles - 1;
  int tile = blockIdx.x;
  if (tile > last) return;

  // clamped index load: always in-bounds, tail values harmlessly unused
  auto load_idx = [&](int t, int& s, int& d) {
    t = (t > last) ? last : t;
    const int e_base = t * 64 + wave * 16;
    const int* ei = (e_base < E) ? eip : ein;
    const int  eo = (e_base < E) ? e_base : (e_base - E);
    s = ei[eo + m];
    d = ei[E + eo + m];
  };

  bf16x8 S[4], D[4];
  {  // prologue: rows of tile0
    int cs, cd;
    load_idx(tile, cs, cd);
    const __bf16* xs = xb + (size_t)cs * HID;
    const __bf16* xd = xb + (size_t)cd * HID;
#pragma unroll
    for (int kt = 0; kt < 4; ++kt) {
      const int k0 = kt * 32 + quad * 8;
      S[kt] = *reinterpret_cast<const bf16x8*>(xs + k0);
      D[kt] = *reinterpret_cast<const bf16x8*>(xd + k0);
    }
  }
  int ns, nd;                      // indices for tile + stride
  load_idx(tile + stride, ns, nd);

  for (; tile <= last; tile += stride) {
    // next tile's row base pointers (consume ns/nd)
    const __bf16* nxs = xb + (size_t)ns * HID;
    const __bf16* nxd = xb + (size_t)nd * HID;
    // issue idx load for tile + 2*stride (arrives by next iteration)
    load_idx(tile + 2 * stride, ns, nd);

    // acc init = b1 broadcast (C layout: col n = m, shared by all 4 rows)
    f32x4 acc[8];
#pragma unroll
    for (int nt = 0; nt < 8; ++nt) {
      f32x4 t;
      t[0] = b1v[nt]; t[1] = b1v[nt]; t[2] = b1v[nt]; t[3] = b1v[nt];
      acc[nt] = t;
    }

#pragma unroll
    for (int kt = 0; kt < 4; ++kt) {
      const int k0 = kt * 32 + quad * 8;
      bf16x8 a;   // h = relu(x_s * x_d), A-frag layout
#pragma unroll
      for (int j = 0; j < 8; ++j) {
        float pr = (float)S[kt][j] * (float)D[kt][j];
        a[j] = (__bf16)fmaxf(pr, 0.f);
      }
      // S[kt]/D[kt] consumed -> refill with next tile's rows (unconditional;
      // clamped-safe). Latency hidden under remaining MFMAs + epilogue.
      S[kt] = *reinterpret_cast<const bf16x8*>(nxs + k0);
      D[kt] = *reinterpret_cast<const bf16x8*>(nxd + k0);
#pragma unroll
      for (int nt = 0; nt < 8; ++nt)
        acc[nt] = __builtin_amdgcn_mfma_f32_16x16x32_bf16(a, Bf[nt][kt], acc[nt], 0, 0, 0);
    }

    // epilogue: p[r] = sum_n relu(C[row][n]) * W2[n]   (bias already in acc)
    float p[4] = {0.f, 0.f, 0.f, 0.f};
#pragma unroll
    for (int nt = 0; nt < 8; ++nt) {
#pragma unroll
      for (int r = 0; r < 4; ++r)
        p[r] = fmaf(fmaxf(acc[nt][r], 0.f), w2v[nt], p[r]);
    }
#pragma unroll
    for (int off = 1; off < 16; off <<= 1) {
#pragma unroll
      for (int r = 0; r < 4; ++r) p[r] += __shfl_xor(p[r], off, 64);
    }
    if (m == 0) {
      float4 o;
      o.x = 1.f / (1.f + __expf(-(p[0] + b2v)));
      o.y = 1.f / (1.f + __expf(-(p[1] + b2v)));
      o.z = 1.f / (1.f + __expf(-(p[2] + b2v)));
      o.w = 1.f / (1.f + __expf(-(p[3] + b2v)));
      *reinterpret_cast<float4*>(out + tile * 64 + wave * 16 + quad * 4) = o;
    }
  }
}

// fp32 fallback (ws too small for xb): unchanged structure
__global__ __launch_bounds__(TPB) void vgae_decode_fallback(
    const float* __restrict__ x,
    const float* __restrict__ W1,
    const float* __restrict__ b1,
    const float* __restrict__ W2,
    const float* __restrict__ b2,
    const int* __restrict__ eip,
    const int* __restrict__ ein,
    float* __restrict__ out,
    int E, int n_tiles)
{
  __shared__ __bf16 sW[HID * PITCH];
  __shared__ float  sb1[HID];
  __shared__ float  sw2[HID];
  for (int c = threadIdx.x; c < HID * (HID / 8); c += TPB) {
    int n = c >> 4, k0 = (c & 15) << 3;
    bf16x8 v;
#pragma unroll
    for (int j = 0; j < 8; ++j) v[j] = (__bf16)W1[(k0 + j) * HID + n];
    *reinterpret_cast<bf16x8*>(&sW[n * PITCH + k0]) = v;
  }
  if (threadIdx.x < HID) { sb1[threadIdx.x] = b1[threadIdx.x]; sw2[threadIdx.x] = W2[threadIdx.x]; }
  __syncthreads();
  const int lane = threadIdx.x & 63, wave = threadIdx.x >> 6;
  const int m = lane & 15, quad = lane >> 4;
  const float b2v = b2[0];
  for (int tile = blockIdx.x; tile < n_tiles; tile += gridDim.x) {
    const int e_base = tile * 64 + wave * 16;
    const int* ei = (e_base < E) ? eip : ein;
    const int  eo = (e_base < E) ? e_base : (e_base - E);
    const int src = ei[eo + m], dst = ei[E + eo + m];
    const float* xs = x + (size_t)src * HID;
    const float* xd = x + (size_t)dst * HID;
    f32x4 acc[8] = {};
#pragma unroll
    for (int kt = 0; kt < 4; ++kt) {
      const int k0 = kt * 32 + quad * 8;
      float4 s0 = *reinterpret_cast<const float4*>(xs + k0);
      float4 s1 = *reinterpret_cast<const float4*>(xs + k0 + 4);
      float4 d0 = *reinterpret_cast<const float4*>(xd + k0);
      float4 d1 = *reinterpret_cast<const float4*>(xd + k0 + 4);
      bf16x8 a;
      a[0] = (__bf16)fmaxf(s0.x * d0.x, 0.f); a[1] = (__bf16)fmaxf(s0.y * d0.y, 0.f);
      a[2] = (__bf16)fmaxf(s0.z * d0.z, 0.f); a[3] = (__bf16)fmaxf(s0.w * d0.w, 0.f);
      a[4] = (__bf16)fmaxf(s1.x * d1.x, 0.f); a[5] = (__bf16)fmaxf(s1.y * d1.y, 0.f);
      a[6] = (__bf16)fmaxf(s1.z * d1.z, 0.f); a[7] = (__bf16)fmaxf(s1.w * d1.w, 0.f);
#pragma unroll
      for (int nt = 0; nt < 8; ++nt) {
        bf16x8 bfr = *reinterpret_cast<const bf16x8*>(&sW[(nt * 16 + m) * PITCH + k0]);
        acc[nt] = __builtin_amdgcn_mfma_f32_16x16x32_bf16(a, bfr, acc[nt], 0, 0, 0);
      }
    }
    float p[4] = {0.f, 0.f, 0.f, 0.f};
#pragma unroll
    for (int nt = 0; nt < 8; ++nt) {
      const int n = nt * 16 + m;
      const float b1n = sb1[n], w2n = sw2[n];
#pragma unroll
      for (int r = 0; r < 4; ++r) p[r] = fmaf(fmaxf(acc[nt][r] + b1n, 0.f), w2n, p[r]);
    }
#pragma unroll
    for (int off = 1; off < 16; off <<= 1)
#pragma unroll
      for (int r = 0; r < 4; ++r) p[r] += __shfl_xor(p[r], off, 64);
    if (m == 0) {
      float4 o;
      o.x = 1.f / (1.f + __expf(-(p[0] + b2v)));
      o.y = 1.f / (1.f + __expf(-(p[1] + b2v)));
      o.z = 1.f / (1.f + __expf(-(p[2] + b2v)));
      o.w = 1.f / (1.f + __expf(-(p[3] + b2v)));
      *reinterpret_cast<float4*>(out + tile * 64 + wave * 16 + quad * 4) = o;
    }
  }
}

extern "C" void kernel_launch(void* const* d_in, const int* in_sizes, int n_in,
                              void* d_out, int out_size, void* d_ws, size_t ws_size,
                              hipStream_t stream) {
  const float* x  = (const float*)d_in[0];
  const float* W1 = (const float*)d_in[1];
  const float* b1 = (const float*)d_in[2];
  const float* W2 = (const float*)d_in[3];
  const float* b2 = (const float*)d_in[4];
  const int*  eip = (const int*)d_in[5];
  const int*  ein = (const int*)d_in[6];
  float* out = (float*)d_out;
  const int E = in_sizes[5] / 2;
  const int n_tiles = (2 * E) / 64;
  const int n_nodes = in_sizes[0] / HID;
  const int n_x4 = in_sizes[0] / 4;

  const size_t w1t_bytes = (size_t)HID * HID * sizeof(__bf16);
  const size_t xb_off    = 65536;
  const size_t xb_bytes  = (size_t)n_nodes * HID * sizeof(__bf16);

  __bf16* w1t = nullptr;
  __bf16* xb  = nullptr;
  if (ws_size >= w1t_bytes) w1t = (__bf16*)d_ws;
  if (ws_size >= xb_off + xb_bytes) xb = (__bf16*)((char*)d_ws + xb_off);

  if (w1t && xb) {
    int prep_grid = (n_x4 + TPB - 1) / TPB;
    if (prep_grid > 6400) prep_grid = 6400;
    prep_kernel<<<prep_grid, TPB, 0, stream>>>(W1, w1t, x, xb, n_x4);
    vgae_decode_kernel<<<512, TPB, 0, stream>>>(xb, w1t, b1, W2, b2,
                                                eip, ein, out, E, n_tiles);
  } else {
    vgae_decode_fallback<<<2560, TPB, 0, stream>>>(x, W1, b1, W2, b2,
                                                   eip, ein, out, E, n_tiles);
  }
}

// Round 3
// 193.160 us; speedup vs baseline: 1.2616x; 1.0320x over previous
//
#include <hip/hip_runtime.h>
#include <hip/hip_bf16.h>

#define HID   128
#define PITCH 136   // only used by the fp32 fallback's LDS tile
#define TPB   256

typedef __attribute__((ext_vector_type(8))) _Float16 f16x8;
typedef __attribute__((ext_vector_type(8))) __bf16  bf16x8;
typedef __attribute__((ext_vector_type(4))) float   f32x4;

// --- prep: grid-stride cast x fp32 -> xh fp16 (16B-wide stores, coalesced).
//     First 2048 global threads also transpose W1 -> w1t[n*HID+k] fp16 via
//     direct global reads (64 KB, L2-hot). No LDS anywhere.
__global__ __launch_bounds__(TPB) void prep_kernel(
    const float* __restrict__ W1, _Float16* __restrict__ w1t,
    const float* __restrict__ x, _Float16* __restrict__ xh, int n_x8) {
  if (xh) {
    for (int i = blockIdx.x * TPB + threadIdx.x; i < n_x8; i += gridDim.x * TPB) {
      float4 a = reinterpret_cast<const float4*>(x)[2 * i];
      float4 b = reinterpret_cast<const float4*>(x)[2 * i + 1];
      f16x8 v;
      v[0] = (_Float16)a.x; v[1] = (_Float16)a.y;
      v[2] = (_Float16)a.z; v[3] = (_Float16)a.w;
      v[4] = (_Float16)b.x; v[5] = (_Float16)b.y;
      v[6] = (_Float16)b.z; v[7] = (_Float16)b.w;
      reinterpret_cast<f16x8*>(xh)[i] = v;
    }
  }
  if (w1t) {
    const int gid = blockIdx.x * TPB + threadIdx.x;
    if (gid < HID * (HID / 8)) {
      const int n  = gid >> 4;
      const int k0 = (gid & 15) << 3;
      f16x8 v;
#pragma unroll
      for (int j = 0; j < 8; ++j) v[j] = (_Float16)W1[(k0 + j) * HID + n];
      *reinterpret_cast<f16x8*>(&w1t[n * HID + k0]) = v;
    }
  }
}

// 16x16x32 f16 MFMA decode, LDS-free, register-resident W1:
//  - all 32 W1 B-fragments in registers (128 regs, loop-invariant)
//  - fp16 datapath: Hadamard+relu = v_pk_mul_f16 + max (was 36 VALU/kt in bf16)
//    -> arch-VGPR diet gets total regs under 256 => 2 waves/SIMD
//  - b1 pre-loaded into the MFMA accumulator; b1/W2 in registers
//  - uniform control flow, clamped index prefetch, per-kt S/D refill pipeline
__global__ __launch_bounds__(TPB, 2) void vgae_decode_kernel(
    const _Float16* __restrict__ xh,
    const _Float16* __restrict__ w1t,
    const float* __restrict__ b1,
    const float* __restrict__ W2,
    const float* __restrict__ b2,
    const int* __restrict__ eip,
    const int* __restrict__ ein,
    float* __restrict__ out,
    int E, int n_tiles)
{
  const int lane = threadIdx.x & 63;
  const int wave = threadIdx.x >> 6;
  const int m    = lane & 15;   // edge-within-wave (A row) / n-col (B col, C col)
  const int quad = lane >> 4;   // k-chunk for A/B frags; C row group
  const float b2v = b2[0];

  // hoist B: 32 x f16x8 = 128 regs, read once per wave (L2-hot)
  f16x8 Bf[8][4];
#pragma unroll
  for (int nt = 0; nt < 8; ++nt)
#pragma unroll
    for (int kt = 0; kt < 4; ++kt)
      Bf[nt][kt] = *reinterpret_cast<const f16x8*>(
          w1t + (nt * 16 + m) * HID + kt * 32 + quad * 8);

  float b1v[8], w2v[8];
#pragma unroll
  for (int nt = 0; nt < 8; ++nt) {
    b1v[nt] = b1[nt * 16 + m];
    w2v[nt] = W2[nt * 16 + m];
  }

  const int stride = gridDim.x;
  const int last   = n_tiles - 1;
  int tile = blockIdx.x;
  if (tile > last) return;

  // clamped index load: always in-bounds, tail values harmlessly unused
  auto load_idx = [&](int t, int& s, int& d) {
    t = (t > last) ? last : t;
    const int e_base = t * 64 + wave * 16;
    const int* ei = (e_base < E) ? eip : ein;
    const int  eo = (e_base < E) ? e_base : (e_base - E);
    s = ei[eo + m];
    d = ei[E + eo + m];
  };

  f16x8 S[4], D[4];
  {  // prologue: rows of tile0
    int cs, cd;
    load_idx(tile, cs, cd);
    const _Float16* xs = xh + (size_t)cs * HID;
    const _Float16* xd = xh + (size_t)cd * HID;
#pragma unroll
    for (int kt = 0; kt < 4; ++kt) {
      const int k0 = kt * 32 + quad * 8;
      S[kt] = *reinterpret_cast<const f16x8*>(xs + k0);
      D[kt] = *reinterpret_cast<const f16x8*>(xd + k0);
    }
  }
  int ns, nd;                      // indices for tile + stride
  load_idx(tile + stride, ns, nd);

  for (; tile <= last; tile += stride) {
    // next tile's row base pointers (consume ns/nd)
    const _Float16* nxs = xh + (size_t)ns * HID;
    const _Float16* nxd = xh + (size_t)nd * HID;
    // issue idx load for tile + 2*stride (arrives by next iteration)
    load_idx(tile + 2 * stride, ns, nd);

    // acc init = b1 broadcast (C layout: col n = m, shared by all 4 rows)
    f32x4 acc[8];
#pragma unroll
    for (int nt = 0; nt < 8; ++nt) {
      f32x4 t;
      t[0] = b1v[nt]; t[1] = b1v[nt]; t[2] = b1v[nt]; t[3] = b1v[nt];
      acc[nt] = t;
    }

#pragma unroll
    for (int kt = 0; kt < 4; ++kt) {
      const int k0 = kt * 32 + quad * 8;
      // h = relu(x_s * x_d) in fp16: vector mul -> v_pk_mul_f16
      f16x8 pr = S[kt] * D[kt];
      f16x8 a;
#pragma unroll
      for (int j = 0; j < 8; ++j) {
        _Float16 v = pr[j];
        a[j] = (v > (_Float16)0) ? v : (_Float16)0;
      }
      // S[kt]/D[kt] consumed -> refill with next tile's rows (unconditional;
      // clamped-safe). Latency hidden under remaining MFMAs + epilogue.
      S[kt] = *reinterpret_cast<const f16x8*>(nxs + k0);
      D[kt] = *reinterpret_cast<const f16x8*>(nxd + k0);
#pragma unroll
      for (int nt = 0; nt < 8; ++nt)
        acc[nt] = __builtin_amdgcn_mfma_f32_16x16x32_f16(a, Bf[nt][kt], acc[nt], 0, 0, 0);
    }

    // epilogue: p[r] = sum_n relu(C[row][n]) * W2[n]   (bias already in acc)
    float p[4] = {0.f, 0.f, 0.f, 0.f};
#pragma unroll
    for (int nt = 0; nt < 8; ++nt) {
#pragma unroll
      for (int r = 0; r < 4; ++r)
        p[r] = fmaf(fmaxf(acc[nt][r], 0.f), w2v[nt], p[r]);
    }
#pragma unroll
    for (int off = 1; off < 16; off <<= 1) {
#pragma unroll
      for (int r = 0; r < 4; ++r) p[r] += __shfl_xor(p[r], off, 64);
    }
    if (m == 0) {
      float4 o;
      o.x = 1.f / (1.f + __expf(-(p[0] + b2v)));
      o.y = 1.f / (1.f + __expf(-(p[1] + b2v)));
      o.z = 1.f / (1.f + __expf(-(p[2] + b2v)));
      o.w = 1.f / (1.f + __expf(-(p[3] + b2v)));
      *reinterpret_cast<float4*>(out + tile * 64 + wave * 16 + quad * 4) = o;
    }
  }
}

// fp32 fallback (ws too small for xh): unchanged structure
__global__ __launch_bounds__(TPB) void vgae_decode_fallback(
    const float* __restrict__ x,
    const float* __restrict__ W1,
    const float* __restrict__ b1,
    const float* __restrict__ W2,
    const float* __restrict__ b2,
    const int* __restrict__ eip,
    const int* __restrict__ ein,
    float* __restrict__ out,
    int E, int n_tiles)
{
  __shared__ __bf16 sW[HID * PITCH];
  __shared__ float  sb1[HID];
  __shared__ float  sw2[HID];
  for (int c = threadIdx.x; c < HID * (HID / 8); c += TPB) {
    int n = c >> 4, k0 = (c & 15) << 3;
    bf16x8 v;
#pragma unroll
    for (int j = 0; j < 8; ++j) v[j] = (__bf16)W1[(k0 + j) * HID + n];
    *reinterpret_cast<bf16x8*>(&sW[n * PITCH + k0]) = v;
  }
  if (threadIdx.x < HID) { sb1[threadIdx.x] = b1[threadIdx.x]; sw2[threadIdx.x] = W2[threadIdx.x]; }
  __syncthreads();
  const int lane = threadIdx.x & 63, wave = threadIdx.x >> 6;
  const int m = lane & 15, quad = lane >> 4;
  const float b2v = b2[0];
  for (int tile = blockIdx.x; tile < n_tiles; tile += gridDim.x) {
    const int e_base = tile * 64 + wave * 16;
    const int* ei = (e_base < E) ? eip : ein;
    const int  eo = (e_base < E) ? e_base : (e_base - E);
    const int src = ei[eo + m], dst = ei[E + eo + m];
    const float* xs = x + (size_t)src * HID;
    const float* xd = x + (size_t)dst * HID;
    f32x4 acc[8] = {};
#pragma unroll
    for (int kt = 0; kt < 4; ++kt) {
      const int k0 = kt * 32 + quad * 8;
      float4 s0 = *reinterpret_cast<const float4*>(xs + k0);
      float4 s1 = *reinterpret_cast<const float4*>(xs + k0 + 4);
      float4 d0 = *reinterpret_cast<const float4*>(xd + k0);
      float4 d1 = *reinterpret_cast<const float4*>(xd + k0 + 4);
      bf16x8 a;
      a[0] = (__bf16)fmaxf(s0.x * d0.x, 0.f); a[1] = (__bf16)fmaxf(s0.y * d0.y, 0.f);
      a[2] = (__bf16)fmaxf(s0.z * d0.z, 0.f); a[3] = (__bf16)fmaxf(s0.w * d0.w, 0.f);
      a[4] = (__bf16)fmaxf(s1.x * d1.x, 0.f); a[5] = (__bf16)fmaxf(s1.y * d1.y, 0.f);
      a[6] = (__bf16)fmaxf(s1.z * d1.z, 0.f); a[7] = (__bf16)fmaxf(s1.w * d1.w, 0.f);
#pragma unroll
      for (int nt = 0; nt < 8; ++nt) {
        bf16x8 bfr = *reinterpret_cast<const bf16x8*>(&sW[(nt * 16 + m) * PITCH + k0]);
        acc[nt] = __builtin_amdgcn_mfma_f32_16x16x32_bf16(a, bfr, acc[nt], 0, 0, 0);
      }
    }
    float p[4] = {0.f, 0.f, 0.f, 0.f};
#pragma unroll
    for (int nt = 0; nt < 8; ++nt) {
      const int n = nt * 16 + m;
      const float b1n = sb1[n], w2n = sw2[n];
#pragma unroll
      for (int r = 0; r < 4; ++r) p[r] = fmaf(fmaxf(acc[nt][r] + b1n, 0.f), w2n, p[r]);
    }
#pragma unroll
    for (int off = 1; off < 16; off <<= 1)
#pragma unroll
      for (int r = 0; r < 4; ++r) p[r] += __shfl_xor(p[r], off, 64);
    if (m == 0) {
      float4 o;
      o.x = 1.f / (1.f + __expf(-(p[0] + b2v)));
      o.y = 1.f / (1.f + __expf(-(p[1] + b2v)));
      o.z = 1.f / (1.f + __expf(-(p[2] + b2v)));
      o.w = 1.f / (1.f + __expf(-(p[3] + b2v)));
      *reinterpret_cast<float4*>(out + tile * 64 + wave * 16 + quad * 4) = o;
    }
  }
}

extern "C" void kernel_launch(void* const* d_in, const int* in_sizes, int n_in,
                              void* d_out, int out_size, void* d_ws, size_t ws_size,
                              hipStream_t stream) {
  const float* x  = (const float*)d_in[0];
  const float* W1 = (const float*)d_in[1];
  const float* b1 = (const float*)d_in[2];
  const float* W2 = (const float*)d_in[3];
  const float* b2 = (const float*)d_in[4];
  const int*  eip = (const int*)d_in[5];
  const int*  ein = (const int*)d_in[6];
  float* out = (float*)d_out;
  const int E = in_sizes[5] / 2;
  const int n_tiles = (2 * E) / 64;
  const int n_nodes = in_sizes[0] / HID;
  const int n_x8 = in_sizes[0] / 8;

  const size_t w1t_bytes = (size_t)HID * HID * sizeof(_Float16);
  const size_t xh_off    = 65536;
  const size_t xh_bytes  = (size_t)n_nodes * HID * sizeof(_Float16);

  _Float16* w1t = nullptr;
  _Float16* xh  = nullptr;
  if (ws_size >= w1t_bytes) w1t = (_Float16*)d_ws;
  if (ws_size >= xh_off + xh_bytes) xh = (_Float16*)((char*)d_ws + xh_off);

  if (w1t && xh) {
    int prep_grid = (n_x8 + TPB - 1) / TPB;
    if (prep_grid > 6400) prep_grid = 6400;
    prep_kernel<<<prep_grid, TPB, 0, stream>>>(W1, w1t, x, xh, n_x8);
    vgae_decode_kernel<<<512, TPB, 0, stream>>>(xh, w1t, b1, W2, b2,
                                                eip, ein, out, E, n_tiles);
  } else {
    vgae_decode_fallback<<<2560, TPB, 0, stream>>>(x, W1, b1, W2, b2,
                                                   eip, ein, out, E, n_tiles);
  }
}

// Round 4
// 189.694 us; speedup vs baseline: 1.2847x; 1.0183x over previous
//
#include <hip/hip_runtime.h>
#include <hip/hip_bf16.h>

#define HID   128
#define PITCH 136   // only used by the fp32 fallback's LDS tile
#define TPB   256

typedef __attribute__((ext_vector_type(8))) _Float16 f16x8;
typedef __attribute__((ext_vector_type(8))) __bf16  bf16x8;
typedef __attribute__((ext_vector_type(4))) float   f32x4;

// DPP-based add of a row-permuted copy: v += perm(v). CTRL is an ICE.
// quad_perm xor1 = 0xB1, xor2 = 0x4E, row_ror:4 = 0x124, row_ror:8 = 0x128.
template <int CTRL>
__device__ __forceinline__ float dpp_add(float v) {
  int x = __builtin_bit_cast(int, v);
  int y = __builtin_amdgcn_update_dpp(0, x, CTRL, 0xF, 0xF, true);
  return v + __builtin_bit_cast(float, y);
}

// --- prep: grid-stride cast x fp32 -> xh fp16 (16B-wide stores, coalesced).
//     First 2048 global threads also transpose W1 -> w1t[n*HID+k] fp16 via
//     direct global reads (64 KB, L2-hot). No LDS anywhere.
__global__ __launch_bounds__(TPB) void prep_kernel(
    const float* __restrict__ W1, _Float16* __restrict__ w1t,
    const float* __restrict__ x, _Float16* __restrict__ xh, int n_x8) {
  if (xh) {
    for (int i = blockIdx.x * TPB + threadIdx.x; i < n_x8; i += gridDim.x * TPB) {
      float4 a = reinterpret_cast<const float4*>(x)[2 * i];
      float4 b = reinterpret_cast<const float4*>(x)[2 * i + 1];
      f16x8 v;
      v[0] = (_Float16)a.x; v[1] = (_Float16)a.y;
      v[2] = (_Float16)a.z; v[3] = (_Float16)a.w;
      v[4] = (_Float16)b.x; v[5] = (_Float16)b.y;
      v[6] = (_Float16)b.z; v[7] = (_Float16)b.w;
      reinterpret_cast<f16x8*>(xh)[i] = v;
    }
  }
  if (w1t) {
    const int gid = blockIdx.x * TPB + threadIdx.x;
    if (gid < HID * (HID / 8)) {
      const int n  = gid >> 4;
      const int k0 = (gid & 15) << 3;
      f16x8 v;
#pragma unroll
      for (int j = 0; j < 8; ++j) v[j] = (_Float16)W1[(k0 + j) * HID + n];
      *reinterpret_cast<f16x8*>(&w1t[n * HID + k0]) = v;
    }
  }
}

// 16x16x32 f16 MFMA decode, LDS-free, register-resident W1:
//  - all 32 W1 B-fragments in registers (128 regs, loop-invariant)
//  - per-tile critical path shortened: packed-f16 relu, a-frags built before
//    refills, refills issued a FULL tile before use, DPP row-reduce (no LDS
//    crossbar ops at all), setprio(1) around the MFMA cluster
//  - b1 pre-loaded into the MFMA accumulator; b1/W2 in registers
__global__ __launch_bounds__(TPB, 2) void vgae_decode_kernel(
    const _Float16* __restrict__ xh,
    const _Float16* __restrict__ w1t,
    const float* __restrict__ b1,
    const float* __restrict__ W2,
    const float* __restrict__ b2,
    const int* __restrict__ eip,
    const int* __restrict__ ein,
    float* __restrict__ out,
    int E, int n_tiles)
{
  const int lane = threadIdx.x & 63;
  const int wave = threadIdx.x >> 6;
  const int m    = lane & 15;   // edge-within-wave (A row) / n-col (B col, C col)
  const int quad = lane >> 4;   // k-chunk for A/B frags; C row group
  const float b2v = b2[0];

  // hoist B: 32 x f16x8 = 128 regs, read once per wave (L2-hot)
  f16x8 Bf[8][4];
#pragma unroll
  for (int nt = 0; nt < 8; ++nt)
#pragma unroll
    for (int kt = 0; kt < 4; ++kt)
      Bf[nt][kt] = *reinterpret_cast<const f16x8*>(
          w1t + (nt * 16 + m) * HID + kt * 32 + quad * 8);

  float b1v[8], w2v[8];
#pragma unroll
  for (int nt = 0; nt < 8; ++nt) {
    b1v[nt] = b1[nt * 16 + m];
    w2v[nt] = W2[nt * 16 + m];
  }

  const int stride = gridDim.x;
  const int last   = n_tiles - 1;
  int tile = blockIdx.x;
  if (tile > last) return;

  // clamped index load: always in-bounds, tail values harmlessly unused
  auto load_idx = [&](int t, int& s, int& d) {
    t = (t > last) ? last : t;
    const int e_base = t * 64 + wave * 16;
    const int* ei = (e_base < E) ? eip : ein;
    const int  eo = (e_base < E) ? e_base : (e_base - E);
    s = ei[eo + m];
    d = ei[E + eo + m];
  };

  f16x8 S[4], D[4];
  {  // prologue: rows of tile0
    int cs, cd;
    load_idx(tile, cs, cd);
    const _Float16* xs = xh + (size_t)cs * HID;
    const _Float16* xd = xh + (size_t)cd * HID;
#pragma unroll
    for (int kt = 0; kt < 4; ++kt) {
      const int k0 = kt * 32 + quad * 8;
      S[kt] = *reinterpret_cast<const f16x8*>(xs + k0);
      D[kt] = *reinterpret_cast<const f16x8*>(xd + k0);
    }
  }
  int ns, nd;                      // indices for tile + stride
  load_idx(tile + stride, ns, nd);

  const f16x8 zero8 = (f16x8)(_Float16)0;

  for (; tile <= last; tile += stride) {
    // next tile's row base pointers (consume ns/nd)
    const _Float16* nxs = xh + (size_t)ns * HID;
    const _Float16* nxd = xh + (size_t)nd * HID;
    // issue idx load for tile + 2*stride (arrives by next iteration)
    load_idx(tile + 2 * stride, ns, nd);

    // 1) build ALL A-fragments first (consumes S/D)
    f16x8 a[4];
#pragma unroll
    for (int kt = 0; kt < 4; ++kt) {
      f16x8 pr = S[kt] * D[kt];                    // v_pk_mul_f16 x4
      a[kt] = __builtin_elementwise_max(pr, zero8); // v_pk_max_f16 x4
    }

    // 2) refill S/D for the NEXT tile now -> full-tile load-to-use slack
#pragma unroll
    for (int kt = 0; kt < 4; ++kt) {
      const int k0 = kt * 32 + quad * 8;
      S[kt] = *reinterpret_cast<const f16x8*>(nxs + k0);
      D[kt] = *reinterpret_cast<const f16x8*>(nxd + k0);
    }

    // 3) acc init = b1 broadcast (C layout: col n = m, shared by all 4 rows)
    f32x4 acc[8];
#pragma unroll
    for (int nt = 0; nt < 8; ++nt) {
      f32x4 t;
      t[0] = b1v[nt]; t[1] = b1v[nt]; t[2] = b1v[nt]; t[3] = b1v[nt];
      acc[nt] = t;
    }

    // 4) MFMA cluster
    __builtin_amdgcn_s_setprio(1);
#pragma unroll
    for (int kt = 0; kt < 4; ++kt)
#pragma unroll
      for (int nt = 0; nt < 8; ++nt)
        acc[nt] = __builtin_amdgcn_mfma_f32_16x16x32_f16(a[kt], Bf[nt][kt], acc[nt], 0, 0, 0);
    __builtin_amdgcn_s_setprio(0);

    // 5) epilogue: p[r] = sum_n relu(C[row][n]) * W2[n]  (bias already in acc)
    float p[4] = {0.f, 0.f, 0.f, 0.f};
#pragma unroll
    for (int nt = 0; nt < 8; ++nt) {
#pragma unroll
      for (int r = 0; r < 4; ++r)
        p[r] = fmaf(fmaxf(acc[nt][r], 0.f), w2v[nt], p[r]);
    }
    // DPP reduce over the 16 m-lanes (one DPP row per quad group): 4 VALU adds
#pragma unroll
    for (int r = 0; r < 4; ++r) {
      p[r] = dpp_add<0xB1>(p[r]);    // quad_perm [1,0,3,2]  : + lane^1
      p[r] = dpp_add<0x4E>(p[r]);    // quad_perm [2,3,0,1]  : + lane^2
      p[r] = dpp_add<0x124>(p[r]);   // row_ror:4            : + 4-group
      p[r] = dpp_add<0x128>(p[r]);   // row_ror:8            : + 8-group
    }
    if (m == 0) {
      float4 o;
      o.x = 1.f / (1.f + __expf(-(p[0] + b2v)));
      o.y = 1.f / (1.f + __expf(-(p[1] + b2v)));
      o.z = 1.f / (1.f + __expf(-(p[2] + b2v)));
      o.w = 1.f / (1.f + __expf(-(p[3] + b2v)));
      *reinterpret_cast<float4*>(out + tile * 64 + wave * 16 + quad * 4) = o;
    }
  }
}

// fp32 fallback (ws too small for xh): unchanged structure
__global__ __launch_bounds__(TPB) void vgae_decode_fallback(
    const float* __restrict__ x,
    const float* __restrict__ W1,
    const float* __restrict__ b1,
    const float* __restrict__ W2,
    const float* __restrict__ b2,
    const int* __restrict__ eip,
    const int* __restrict__ ein,
    float* __restrict__ out,
    int E, int n_tiles)
{
  __shared__ __bf16 sW[HID * PITCH];
  __shared__ float  sb1[HID];
  __shared__ float  sw2[HID];
  for (int c = threadIdx.x; c < HID * (HID / 8); c += TPB) {
    int n = c >> 4, k0 = (c & 15) << 3;
    bf16x8 v;
#pragma unroll
    for (int j = 0; j < 8; ++j) v[j] = (__bf16)W1[(k0 + j) * HID + n];
    *reinterpret_cast<bf16x8*>(&sW[n * PITCH + k0]) = v;
  }
  if (threadIdx.x < HID) { sb1[threadIdx.x] = b1[threadIdx.x]; sw2[threadIdx.x] = W2[threadIdx.x]; }
  __syncthreads();
  const int lane = threadIdx.x & 63, wave = threadIdx.x >> 6;
  const int m = lane & 15, quad = lane >> 4;
  const float b2v = b2[0];
  for (int tile = blockIdx.x; tile < n_tiles; tile += gridDim.x) {
    const int e_base = tile * 64 + wave * 16;
    const int* ei = (e_base < E) ? eip : ein;
    const int  eo = (e_base < E) ? e_base : (e_base - E);
    const int src = ei[eo + m], dst = ei[E + eo + m];
    const float* xs = x + (size_t)src * HID;
    const float* xd = x + (size_t)dst * HID;
    f32x4 acc[8] = {};
#pragma unroll
    for (int kt = 0; kt < 4; ++kt) {
      const int k0 = kt * 32 + quad * 8;
      float4 s0 = *reinterpret_cast<const float4*>(xs + k0);
      float4 s1 = *reinterpret_cast<const float4*>(xs + k0 + 4);
      float4 d0 = *reinterpret_cast<const float4*>(xd + k0);
      float4 d1 = *reinterpret_cast<const float4*>(xd + k0 + 4);
      bf16x8 a;
      a[0] = (__bf16)fmaxf(s0.x * d0.x, 0.f); a[1] = (__bf16)fmaxf(s0.y * d0.y, 0.f);
      a[2] = (__bf16)fmaxf(s0.z * d0.z, 0.f); a[3] = (__bf16)fmaxf(s0.w * d0.w, 0.f);
      a[4] = (__bf16)fmaxf(s1.x * d1.x, 0.f); a[5] = (__bf16)fmaxf(s1.y * d1.y, 0.f);
      a[6] = (__bf16)fmaxf(s1.z * d1.z, 0.f); a[7] = (__bf16)fmaxf(s1.w * d1.w, 0.f);
#pragma unroll
      for (int nt = 0; nt < 8; ++nt) {
        bf16x8 bfr = *reinterpret_cast<const bf16x8*>(&sW[(nt * 16 + m) * PITCH + k0]);
        acc[nt] = __builtin_amdgcn_mfma_f32_16x16x32_bf16(a, bfr, acc[nt], 0, 0, 0);
      }
    }
    float p[4] = {0.f, 0.f, 0.f, 0.f};
#pragma unroll
    for (int nt = 0; nt < 8; ++nt) {
      const int n = nt * 16 + m;
      const float b1n = sb1[n], w2n = sw2[n];
#pragma unroll
      for (int r = 0; r < 4; ++r) p[r] = fmaf(fmaxf(acc[nt][r] + b1n, 0.f), w2n, p[r]);
    }
#pragma unroll
    for (int off = 1; off < 16; off <<= 1)
#pragma unroll
      for (int r = 0; r < 4; ++r) p[r] += __shfl_xor(p[r], off, 64);
    if (m == 0) {
      float4 o;
      o.x = 1.f / (1.f + __expf(-(p[0] + b2v)));
      o.y = 1.f / (1.f + __expf(-(p[1] + b2v)));
      o.z = 1.f / (1.f + __expf(-(p[2] + b2v)));
      o.w = 1.f / (1.f + __expf(-(p[3] + b2v)));
      *reinterpret_cast<float4*>(out + tile * 64 + wave * 16 + quad * 4) = o;
    }
  }
}

extern "C" void kernel_launch(void* const* d_in, const int* in_sizes, int n_in,
                              void* d_out, int out_size, void* d_ws, size_t ws_size,
                              hipStream_t stream) {
  const float* x  = (const float*)d_in[0];
  const float* W1 = (const float*)d_in[1];
  const float* b1 = (const float*)d_in[2];
  const float* W2 = (const float*)d_in[3];
  const float* b2 = (const float*)d_in[4];
  const int*  eip = (const int*)d_in[5];
  const int*  ein = (const int*)d_in[6];
  float* out = (float*)d_out;
  const int E = in_sizes[5] / 2;
  const int n_tiles = (2 * E) / 64;
  const int n_nodes = in_sizes[0] / HID;
  const int n_x8 = in_sizes[0] / 8;

  const size_t w1t_bytes = (size_t)HID * HID * sizeof(_Float16);
  const size_t xh_off    = 65536;
  const size_t xh_bytes  = (size_t)n_nodes * HID * sizeof(_Float16);

  _Float16* w1t = nullptr;
  _Float16* xh  = nullptr;
  if (ws_size >= w1t_bytes) w1t = (_Float16*)d_ws;
  if (ws_size >= xh_off + xh_bytes) xh = (_Float16*)((char*)d_ws + xh_off);

  if (w1t && xh) {
    int prep_grid = (n_x8 + TPB - 1) / TPB;
    if (prep_grid > 6400) prep_grid = 6400;
    prep_kernel<<<prep_grid, TPB, 0, stream>>>(W1, w1t, x, xh, n_x8);
    vgae_decode_kernel<<<512, TPB, 0, stream>>>(xh, w1t, b1, W2, b2,
                                                eip, ein, out, E, n_tiles);
  } else {
    vgae_decode_fallback<<<2560, TPB, 0, stream>>>(x, W1, b1, W2, b2,
                                                   eip, ein, out, E, n_tiles);
  }
}